// Round 7
// baseline (110.201 us; speedup 1.0000x reference)
//
#include <hip/hip_runtime.h>
#include <hip/hip_bf16.h>
#include <cstdint>

#define Bc 2
#define Nc 3072
#define Hc 4
#define NW32 96      // 32-key tiles per row

typedef __bf16 bf16x8 __attribute__((ext_vector_type(8)));
typedef float  f32x16 __attribute__((ext_vector_type(16)));

#define QSCALE 0.18033688f   // 0.125 * log2(e): exp(s/8) == exp2(s*QSCALE)

static __device__ __forceinline__ f32x16 mfma32(bf16x8 a, bf16x8 b, f32x16 c) {
    return __builtin_amdgcn_mfma_f32_32x32x16_bf16(a, b, c, 0, 0, 0);
}
static __device__ __forceinline__ void gload_lds16(const void* g, void* l) {
    __builtin_amdgcn_global_load_lds((const __attribute__((address_space(1))) void*)g,
                                     (__attribute__((address_space(3))) void*)l, 16, 0, 0);
}
static __device__ __forceinline__ uint32_t cvtpk(float lo, float hi) {
    uint32_t w;
    asm("v_cvt_pk_bf16_f32 %0, %1, %2" : "=v"(w) : "v"(lo), "v"(hi));
    return w;
}

// softmax for one 32-row chain: leaky+exp2, pack to bf16 pairs, mask packed word,
// accumulate denominator from the SAME masked quantized values.
static __device__ __forceinline__ void softmax_pack(const f32x16& sc, uint32_t mwh,
                                                    uint32_t W8[8], float& lsum)
{
    #pragma unroll
    for (int i = 0; i < 8; ++i) {
        const int bp0 = (2*i & 3) + 8*(2*i >> 2);   // bp1 = bp0+1
        float s0 = sc[2*i], s1 = sc[2*i + 1];
        float a0 = fmaxf(s0, 0.2f*s0);
        float a1 = fmaxf(s1, 0.2f*s1);
        float e0, e1;
        asm("v_exp_f32 %0, %1" : "=v"(e0) : "v"(a0));   // exp2 (log2e pre-folded)
        asm("v_exp_f32 %0, %1" : "=v"(e1) : "v"(a1));
        uint32_t pk = cvtpk(e0, e1);
        uint32_t m0 = (uint32_t)(((int)(mwh << (31 - bp0))) >> 31);
        uint32_t m1 = (uint32_t)(((int)(mwh << (30 - bp0))) >> 31);
        uint32_t wv = pk & ((m0 & 0x0000ffffu) | (m1 & 0xffff0000u));
        W8[i] = wv;
        lsum += __uint_as_float(wv << 16);
        lsum += __uint_as_float(wv & 0xffff0000u);
    }
}

static __device__ __forceinline__ void assemble_pa(uint32_t W8[8], bf16x8& pa0, bf16x8& pa1)
{
    uint32_t a0 = W8[0], a2 = W8[2], a1 = W8[1], a3 = W8[3];
    uint32_t b0 = W8[4], b2 = W8[6], b1 = W8[5], b3 = W8[7];
    asm("v_permlane32_swap_b32 %0, %1" : "+v"(a0), "+v"(a2));
    asm("v_permlane32_swap_b32 %0, %1" : "+v"(a1), "+v"(a3));
    asm("v_permlane32_swap_b32 %0, %1" : "+v"(b0), "+v"(b2));
    asm("v_permlane32_swap_b32 %0, %1" : "+v"(b1), "+v"(b3));
    union { uint32_t u[4]; bf16x8 v; } u0, u1;
    u0.u[0] = a0; u0.u[1] = a1; u0.u[2] = a2; u0.u[3] = a3;
    u1.u[0] = b0; u1.u[1] = b1; u1.u[2] = b2; u1.u[3] = b3;
    pa0 = u0.v; pa1 = u1.v;
}

// ---- fused prep: W -> bf16 hi/lo [p][h][o][d] (+bias), x -> bf16 hi/lo planes ----
__global__ void prep_kernel(const float* __restrict__ Wq, const float* __restrict__ Wk,
                            const float* __restrict__ Wv,
                            const float* __restrict__ bq, const float* __restrict__ bk,
                            const float* __restrict__ bv, const float* __restrict__ x,
                            __bf16* __restrict__ Wbh, __bf16* __restrict__ Wbl,
                            float* __restrict__ Bs,
                            __bf16* __restrict__ Xh, __bf16* __restrict__ Xl)
{
    if (blockIdx.x < 192) {
        int i = blockIdx.x*256 + threadIdx.x;   // 49152
        int d = i & 63, o = (i >> 6) & 63, h = (i >> 12) & 3, p = i >> 14;
        const float* W = (p == 0) ? Wq : (p == 1) ? Wk : Wv;
        float scale = (p == 0) ? QSCALE : 1.0f;
        float val = W[(h*64 + d)*64 + o] * scale;
        int idx = (((p*Hc + h)*64 + o) << 6) + d;
        __bf16 hi = (__bf16)val;
        Wbh[idx] = hi;
        Wbl[idx] = (__bf16)(val - (float)hi);
        if (i < 3*Hc*64) {
            int pp = i / (Hc*64), rest = i % (Hc*64);
            const float* B = (pp == 0) ? bq : (pp == 1) ? bk : bv;
            Bs[i] = B[rest] * ((pp == 0) ? QSCALE : 1.0f);
        }
    } else {
        int i = (blockIdx.x - 192)*256 + threadIdx.x;   // 49152 x 8 elems
        const float4* xp = (const float4*)(x + (size_t)i*8);
        float4 a = xp[0], c = xp[1];
        float v[8] = {a.x, a.y, a.z, a.w, c.x, c.y, c.z, c.w};
        bf16x8 h, l;
        #pragma unroll
        for (int j = 0; j < 8; ++j) {
            __bf16 hh = (__bf16)v[j];
            h[j] = hh;
            l[j] = (__bf16)(v[j] - (float)hh);
        }
        *(bf16x8*)(Xh + (size_t)i*8) = h;
        *(bf16x8*)(Xl + (size_t)i*8) = l;
    }
}

// ---- QKV projection via MFMA. Q,K -> flat [bh][n][64] hi/lo; V -> KVimg granules ----
__global__ __launch_bounds__(256) void qkv_mfma(
    const __bf16* __restrict__ Xh, const __bf16* __restrict__ Xl,
    const __bf16* __restrict__ Wbh, const __bf16* __restrict__ Wbl,
    const float* __restrict__ Bs,
    __bf16* __restrict__ Qh, __bf16* __restrict__ Ql,
    __bf16* __restrict__ Kh, __bf16* __restrict__ Kl,
    __bf16* __restrict__ KVimg)
{
    const int lane = threadIdx.x & 63, w = threadIdx.x >> 6;
    const int l31 = lane & 31, hi = lane >> 5;
    int t = blockIdx.x;                 // 1152 blocks
    int nt = t % 48; t /= 48;
    int b  = t & 1;  t >>= 1;
    int p  = t % 3;
    int h  = t / 3;
    const int r0 = (w >> 1)*32, c0 = (w & 1)*32, n0 = nt*64;

    bf16x8 xh[4], xl[4], wh[4], wl[4];
    #pragma unroll
    for (int kk = 0; kk < 4; ++kk) {
        size_t xoff = (((size_t)(b*Nc + n0 + r0 + l31)) << 6) + kk*16 + hi*8;
        xh[kk] = *(const bf16x8*)(Xh + xoff);
        xl[kk] = *(const bf16x8*)(Xl + xoff);
        size_t woff = (((size_t)((p*Hc + h)*64 + c0 + l31)) << 6) + kk*16 + hi*8;
        wh[kk] = *(const bf16x8*)(Wbh + woff);
        wl[kk] = *(const bf16x8*)(Wbl + woff);
    }
    float bias = Bs[(p*Hc + h)*64 + c0 + l31];
    f32x16 acc;
    #pragma unroll
    for (int i = 0; i < 16; ++i) acc[i] = bias;
    #pragma unroll
    for (int kk = 0; kk < 4; ++kk) {
        acc = mfma32(xh[kk], wh[kk], acc);
        acc = mfma32(xl[kk], wh[kk], acc);
        acc = mfma32(xh[kk], wl[kk], acc);
    }
    const int bh = b*Hc + h;
    if (p < 2) {
        __bf16* dh = (p == 0) ? Qh : Kh;
        __bf16* dl = (p == 0) ? Ql : Kl;
        #pragma unroll
        for (int r = 0; r < 16; ++r) {
            int row = (r & 3) + 8*(r >> 2) + 4*hi;
            size_t idx = (((size_t)bh*Nc + n0 + r0 + row) << 6) + c0 + l31;
            float val = acc[r];
            __bf16 hh = (__bf16)val;
            dh[idx] = hh;
            dl[idx] = (__bf16)(val - (float)hh);
        }
    } else {
        // V: write image granules directly (granule (kb,o) = V[kb*8..+7][o])
        const int t_img = (n0 + r0) >> 5;
        char* img = (char*)KVimg + (((size_t)bh*96 + t_img) << 14);
        #pragma unroll
        for (int grp = 0; grp < 2; ++grp) {       // acc regs grp*8 .. grp*8+7
            uint32_t wH[4], wL[4];
            #pragma unroll
            for (int j = 0; j < 4; ++j) {
                float a0 = acc[grp*8 + 2*j], a1 = acc[grp*8 + 2*j + 1];
                uint32_t ww = cvtpk(a0, a1);
                wH[j] = ww;
                float l0 = a0 - __uint_as_float(ww << 16);
                float l1 = a1 - __uint_as_float(ww & 0xffff0000u);
                wL[j] = cvtpk(l0, l1);
            }
            asm("v_permlane32_swap_b32 %0, %1" : "+v"(wH[0]), "+v"(wH[2]));
            asm("v_permlane32_swap_b32 %0, %1" : "+v"(wH[1]), "+v"(wH[3]));
            asm("v_permlane32_swap_b32 %0, %1" : "+v"(wL[0]), "+v"(wL[2]));
            asm("v_permlane32_swap_b32 %0, %1" : "+v"(wL[1]), "+v"(wL[3]));
            const int kb = grp*2 + hi;
            const int o  = c0 + l31;
            uint4 gh = {wH[0], wH[1], wH[2], wH[3]};
            uint4 gl = {wL[0], wL[1], wL[2], wL[3]};
            *(uint4*)(img + 8192 + ((kb*64 + o) << 4)) = gh;
            *(uint4*)(img + 8192 + 4096 + ((kb*64 + o) << 4)) = gl;
        }
    }
}

// ---- K image: granule (dc,key) = K[key][dc*8..+7] (hi at 0, lo at +4096) ----
__global__ void imgk_kernel(const __bf16* __restrict__ Kh, const __bf16* __restrict__ Kl,
                            __bf16* __restrict__ KVimg)
{
    const int tid = threadIdx.x;
    const int t = blockIdx.x % 96, bh = blockIdx.x / 96;
    char* img = (char*)KVimg + (((size_t)bh*96 + t) << 14);
    int dc = tid & 7, key = tid >> 3;
    size_t src = (((size_t)bh*Nc + t*32 + key) << 6) + dc*8;
    *(uint4*)(img + (dc*32 + key)*16)        = *(const uint4*)(Kh + src);
    *(uint4*)(img + 4096 + (dc*32 + key)*16) = *(const uint4*)(Kl + src);
}

// ---- pack adjacency transposed: pmT[b][w][n], bit j = edge[b][n][32w+j] ----
__global__ void pack_kernel(const int* __restrict__ edge, uint32_t* __restrict__ pmT)
{
    int gw = blockIdx.x*4 + (threadIdx.x >> 6);
    int lane = threadIdx.x & 63;
    int ng = gw % 48; gw /= 48;
    int w  = gw % NW32; gw /= NW32;
    int b  = gw;
    int n = ng*64 + lane;
    const uint4* ep = (const uint4*)(edge + ((size_t)b*Nc + n)*Nc + w*32);
    uint32_t word = 0;
    #pragma unroll
    for (int i = 0; i < 8; ++i) {
        uint4 e = ep[i];
        word |= (e.x ? 1u : 0u) << (4*i);
        word |= (e.y ? 1u : 0u) << (4*i + 1);
        word |= (e.z ? 1u : 0u) << (4*i + 2);
        word |= (e.w ? 1u : 0u) << (4*i + 3);
    }
    pmT[((size_t)b*NW32 + w)*Nc + n] = word;
}

// ---- flash attention: 64 q-rows/wave (2 interleaved chains), counted-vmcnt pipeline ----
__global__ __launch_bounds__(256, 2) void attn_mfma(
    const __bf16* __restrict__ Qh, const __bf16* __restrict__ Ql,
    const __bf16* __restrict__ KVimg, const uint32_t* __restrict__ pmT,
    float* __restrict__ PA, float* __restrict__ PL, int KS, int tps)
{
    __shared__ __align__(16) char ldsKV[2][16384];
    const int lane = threadIdx.x & 63, w = threadIdx.x >> 6;
    const int l31 = lane & 31, hi = lane >> 5;
    int gb = blockIdx.x;
    const int bh = gb & 7; gb >>= 3;        // XCD swizzle: one bh per XCD
    const int qt = gb % 12;
    const int ks = gb / 12;
    const int b = bh >> 2;
    const int qrow0 = qt*256 + w*64;        // chain c covers qrow0 + c*32 + l31
    const int t0 = ks*tps;

    // masks for tile t0 (both chains), loaded BEFORE stage: vmcnt(6) covers 2+4
    const uint32_t* pmp = pmT + ((size_t)b*NW32 + t0)*Nc + qrow0 + l31;
    uint32_t mw0 = pmp[0];
    uint32_t mw1 = pmp[32];
    __builtin_amdgcn_sched_barrier(0);
    const char* gsrc = (const char*)KVimg + (((size_t)bh*96 + t0) << 14)
                     + w*4096 + lane*16;
    #pragma unroll
    for (int g = 0; g < 4; ++g)
        gload_lds16(gsrc + g*1024, &ldsKV[0][w*4096 + g*1024]);

    // Q B-frags for both chains (col = q-row = l31, k = d), pre-scaled by QSCALE
    bf16x8 qh0[4], ql0[4], qh1[4], ql1[4];
    #pragma unroll
    for (int kk = 0; kk < 4; ++kk) {
        size_t qa = (((size_t)bh*Nc + qrow0 + l31) << 6) + kk*16 + hi*8;
        qh0[kk] = *(const bf16x8*)(Qh + qa);
        ql0[kk] = *(const bf16x8*)(Ql + qa);
        qh1[kk] = *(const bf16x8*)(Qh + qa + (32 << 6));
        ql1[kk] = *(const bf16x8*)(Ql + qa + (32 << 6));
    }

    f32x16 acc00, acc01, acc10, acc11;   // [chain][o-tile]
    #pragma unroll
    for (int i = 0; i < 16; ++i) { acc00[i] = 0.f; acc01[i] = 0.f; acc10[i] = 0.f; acc11[i] = 0.f; }
    float lsum0 = 0.f, lsum1 = 0.f;

    int cur = 0;
    #pragma unroll 1
    for (int it = 0; it < tps; ++it) {
        const int adv = (it + 1 < tps) ? 1 : 0;
        // prefetch next masks FIRST, then next stage -> vmcnt(6) retires current tile
        uint32_t nmw0 = pmp[(size_t)adv*Nc];
        uint32_t nmw1 = pmp[(size_t)adv*Nc + 32];
        pmp += (size_t)adv*Nc;
        __builtin_amdgcn_sched_barrier(0);
        const char* gnext = gsrc + ((size_t)adv << 14);
        {
            char* ldst = &ldsKV[cur ^ 1][w*4096];
            #pragma unroll
            for (int g = 0; g < 4; ++g)
                gload_lds16(gnext + g*1024, ldst + g*1024);
        }
        gsrc = gnext;
        asm volatile("s_waitcnt vmcnt(6)" ::: "memory");
        __builtin_amdgcn_s_barrier();
        const char* Lb = &ldsKV[cur][0];

        // ---- QK^T: 24 MFMA, two independent accumulator streams ----
        f32x16 sc0, sc1;
        #pragma unroll
        for (int i = 0; i < 16; ++i) { sc0[i] = 0.f; sc1[i] = 0.f; }
        __builtin_amdgcn_s_setprio(1);
        #pragma unroll
        for (int kk = 0; kk < 4; ++kk) {
            bf16x8 ka = *(const bf16x8*)(Lb + ((kk*2 + hi) << 9) + (l31 << 4));
            bf16x8 la = *(const bf16x8*)(Lb + 4096 + ((kk*2 + hi) << 9) + (l31 << 4));
            sc0 = mfma32(ka, qh0[kk], sc0);
            sc1 = mfma32(ka, qh1[kk], sc1);
            sc0 = mfma32(la, qh0[kk], sc0);
            sc1 = mfma32(la, qh1[kk], sc1);
            sc0 = mfma32(ka, ql0[kk], sc0);
            sc1 = mfma32(ka, ql1[kk], sc1);
        }
        __builtin_amdgcn_s_setprio(0);

        // ---- in-register softmax, both chains (independent VALU streams) ----
        uint32_t W80[8], W81[8];
        softmax_pack(sc0, mw0 >> (hi*4), W80, lsum0);
        softmax_pack(sc1, mw1 >> (hi*4), W81, lsum1);
        mw0 = nmw0; mw1 = nmw1;

        bf16x8 pa00, pa01, pa10, pa11;
        assemble_pa(W80, pa00, pa01);
        assemble_pa(W81, pa10, pa11);

        // ---- PV: 16 MFMA, V fragments read once and shared by both chains ----
        __builtin_amdgcn_s_setprio(1);
        #pragma unroll
        for (int kkp = 0; kkp < 2; ++kkp) {
            bf16x8 pc0 = kkp ? pa01 : pa00;
            bf16x8 pc1 = kkp ? pa11 : pa10;
            #pragma unroll
            for (int ot = 0; ot < 2; ++ot) {
                bf16x8 vh = *(const bf16x8*)(Lb + 8192 + ((kkp*2 + hi) << 10)
                                             + ((ot*32 + l31) << 4));
                bf16x8 vl = *(const bf16x8*)(Lb + 12288 + ((kkp*2 + hi) << 10)
                                             + ((ot*32 + l31) << 4));
                if (ot == 0) {
                    acc00 = mfma32(pc0, vh, acc00); acc00 = mfma32(pc0, vl, acc00);
                    acc10 = mfma32(pc1, vh, acc10); acc10 = mfma32(pc1, vl, acc10);
                } else {
                    acc01 = mfma32(pc0, vh, acc01); acc01 = mfma32(pc0, vl, acc01);
                    acc11 = mfma32(pc1, vh, acc11); acc11 = mfma32(pc1, vl, acc11);
                }
            }
        }
        __builtin_amdgcn_s_setprio(0);

        asm volatile("" ::: "memory");
        __builtin_amdgcn_s_barrier();
        cur ^= 1;
    }

    // ---- epilogue: PA[bh][ks][n][o], PL[bh][ks][n] ----
    #pragma unroll
    for (int c = 0; c < 2; ++c) {
        float* po = PA + (((size_t)(bh*KS + ks)*Nc + qrow0 + c*32) << 6);
        #pragma unroll
        for (int r = 0; r < 16; ++r) {
            int row = (r & 3) + 8*(r >> 2) + 4*hi;
            po[((size_t)row << 6) + l31]      = c ? acc10[r] : acc00[r];
            po[((size_t)row << 6) + 32 + l31] = c ? acc11[r] : acc01[r];
        }
        float ls = c ? lsum1 : lsum0;
        ls += __shfl_xor(ls, 32);
        if (lane < 32)
            PL[(size_t)(bh*KS + ks)*Nc + qrow0 + c*32 + l31] = ls;
    }
}

// ---- merge: sum key-splits, divide, mean heads, leaky ----
__global__ void merge_kernel(const float* __restrict__ PA, const float* __restrict__ PL,
                             float* __restrict__ out, int KS)
{
    int gid = blockIdx.x*256 + threadIdx.x;
    int o  = gid & 63;
    int bn = gid >> 6;
    int n  = bn % Nc;
    int b  = bn / Nc;
    float ft = 0.f;
    for (int h = 0; h < Hc; ++h) {
        int bh = b*Hc + h;
        float A = 0.f, L = 0.f;
        for (int ks = 0; ks < KS; ++ks) {
            A += PA[(((size_t)(bh*KS + ks)*Nc + n) << 6) + o];
            L += PL[(size_t)(bh*KS + ks)*Nc + n];
        }
        ft += A / L;
    }
    ft *= 0.25f;
    out[((size_t)bn << 6) + o] = fmaxf(ft, 0.f) + 0.2f*fminf(ft, 0.f);
}

extern "C" void kernel_launch(void* const* d_in, const int* in_sizes, int n_in,
                              void* d_out, int out_size, void* d_ws, size_t ws_size,
                              hipStream_t stream)
{
    const float* x    = (const float*)d_in[0];
    const int*   edge = (const int*)d_in[1];
    const float* Wv   = (const float*)d_in[2];
    const float* bv   = (const float*)d_in[3];
    const float* Wq   = (const float*)d_in[4];
    const float* bq   = (const float*)d_in[5];
    const float* Wk   = (const float*)d_in[6];
    const float* bk   = (const float*)d_in[7];
    float* out = (float*)d_out;

    const size_t PROJ = (size_t)Bc*Hc*Nc*64;
    char* p = (char*)d_ws;
    __bf16* Wbh = (__bf16*)p;   p += 49152*2;
    __bf16* Wbl = (__bf16*)p;   p += 49152*2;
    float*  Bs  = (float*)p;    p += 4096;
    __bf16* Xh  = (__bf16*)p;   p += (size_t)Bc*Nc*64*2;
    __bf16* Xl  = (__bf16*)p;   p += (size_t)Bc*Nc*64*2;
    __bf16* Qh  = (__bf16*)p;   p += PROJ*2;
    __bf16* Ql  = (__bf16*)p;   p += PROJ*2;
    __bf16* Kh  = (__bf16*)p;   p += PROJ*2;
    __bf16* Kl  = (__bf16*)p;   p += PROJ*2;
    __bf16* KVimg = (__bf16*)p; p += ((size_t)Bc*Hc*96) << 14;
    uint32_t* pmT = (uint32_t*)p; p += (size_t)Bc*NW32*Nc*4;

    int KS = 8;   // grid 768 = 3 blocks/CU dispatched
    for (;;) {
        size_t need = (size_t)(p - (char*)d_ws)
                    + (size_t)Bc*Hc*KS*Nc*64*4 + (size_t)Bc*Hc*KS*Nc*4;
        if (need <= ws_size || KS == 1) break;
        KS >>= 1;
    }
    float* PA = (float*)p;      p += (size_t)Bc*Hc*KS*Nc*64*4;
    float* PL = (float*)p;

    hipLaunchKernelGGL(prep_kernel, dim3(384),  dim3(256), 0, stream,
                       Wq, Wk, Wv, bq, bk, bv, x, Wbh, Wbl, Bs, Xh, Xl);
    hipLaunchKernelGGL(qkv_mfma,    dim3(1152), dim3(256), 0, stream,
                       Xh, Xl, Wbh, Wbl, Bs, Qh, Ql, Kh, Kl, KVimg);
    hipLaunchKernelGGL(imgk_kernel, dim3(Bc*Hc*96), dim3(256), 0, stream, Kh, Kl, KVimg);
    hipLaunchKernelGGL(pack_kernel, dim3(Bc*NW32*48/4), dim3(256), 0, stream, edge, pmT);
    hipLaunchKernelGGL(attn_mfma,   dim3(8*KS*12), dim3(256), 0, stream,
                       Qh, Ql, KVimg, pmT, PA, PL, KS, 96/KS);
    hipLaunchKernelGGL(merge_kernel, dim3((Bc*Nc*64)/256), dim3(256), 0, stream,
                       PA, PL, out, KS);
}

// Round 8
// 89.178 us; speedup vs baseline: 1.2357x; 1.2357x over previous
//
#include <hip/hip_runtime.h>
#include <hip/hip_bf16.h>
#include <cstdint>

#define Bc 2
#define Nc 3072
#define Hc 4
#define NW32 96      // 32-key tiles per row
#define TILEB 12288  // bytes per 32-key KV image tile: Kh 4K | Kl 4K | Vh 4K

typedef __bf16 bf16x8 __attribute__((ext_vector_type(8)));
typedef float  f32x16 __attribute__((ext_vector_type(16)));

#define QSCALE 0.18033688f   // 0.125 * log2(e): exp(s/8) == exp2(s*QSCALE)

static __device__ __forceinline__ f32x16 mfma32(bf16x8 a, bf16x8 b, f32x16 c) {
    return __builtin_amdgcn_mfma_f32_32x32x16_bf16(a, b, c, 0, 0, 0);
}
static __device__ __forceinline__ void gload_lds16(const void* g, void* l) {
    __builtin_amdgcn_global_load_lds((const __attribute__((address_space(1))) void*)g,
                                     (__attribute__((address_space(3))) void*)l, 16, 0, 0);
}
static __device__ __forceinline__ uint32_t cvtpk(float lo, float hi) {
    uint32_t w;
    asm("v_cvt_pk_bf16_f32 %0, %1, %2" : "=v"(w) : "v"(lo), "v"(hi));
    return w;
}

// softmax for one 32-key sub-tile: leaky+exp2, pack to bf16 pairs, mask packed word.
static __device__ __forceinline__ void softmax_pack(const f32x16& sc, uint32_t mwh,
                                                    uint32_t W8[8])
{
    #pragma unroll
    for (int i = 0; i < 8; ++i) {
        const int bp0 = (2*i & 3) + 8*(2*i >> 2);   // bp1 = bp0+1
        float s0 = sc[2*i], s1 = sc[2*i + 1];
        float a0 = fmaxf(s0, 0.2f*s0);
        float a1 = fmaxf(s1, 0.2f*s1);
        float e0, e1;
        asm("v_exp_f32 %0, %1" : "=v"(e0) : "v"(a0));   // exp2 (log2e pre-folded)
        asm("v_exp_f32 %0, %1" : "=v"(e1) : "v"(a1));
        uint32_t pk = cvtpk(e0, e1);
        uint32_t m0 = (uint32_t)(((int)(mwh << (31 - bp0))) >> 31);
        uint32_t m1 = (uint32_t)(((int)(mwh << (30 - bp0))) >> 31);
        W8[i] = pk & ((m0 & 0x0000ffffu) | (m1 & 0xffff0000u));
    }
}

static __device__ __forceinline__ void assemble_pa(uint32_t W8[8], bf16x8& pa0, bf16x8& pa1)
{
    uint32_t a0 = W8[0], a2 = W8[2], a1 = W8[1], a3 = W8[3];
    uint32_t b0 = W8[4], b2 = W8[6], b1 = W8[5], b3 = W8[7];
    asm("v_permlane32_swap_b32 %0, %1" : "+v"(a0), "+v"(a2));
    asm("v_permlane32_swap_b32 %0, %1" : "+v"(a1), "+v"(a3));
    asm("v_permlane32_swap_b32 %0, %1" : "+v"(b0), "+v"(b2));
    asm("v_permlane32_swap_b32 %0, %1" : "+v"(b1), "+v"(b3));
    union { uint32_t u[4]; bf16x8 v; } u0, u1;
    u0.u[0] = a0; u0.u[1] = a1; u0.u[2] = a2; u0.u[3] = a3;
    u1.u[0] = b0; u1.u[1] = b1; u1.u[2] = b2; u1.u[3] = b3;
    pa0 = u0.v; pa1 = u1.v;
}

// ---- fused prep: W -> bf16 hi/lo [p][h][o][d] (+bias), x -> bf16 hi/lo planes ----
__global__ void prep_kernel(const float* __restrict__ Wq, const float* __restrict__ Wk,
                            const float* __restrict__ Wv,
                            const float* __restrict__ bq, const float* __restrict__ bk,
                            const float* __restrict__ bv, const float* __restrict__ x,
                            __bf16* __restrict__ Wbh, __bf16* __restrict__ Wbl,
                            float* __restrict__ Bs,
                            __bf16* __restrict__ Xh, __bf16* __restrict__ Xl)
{
    if (blockIdx.x < 192) {
        int i = blockIdx.x*256 + threadIdx.x;   // 49152
        int d = i & 63, o = (i >> 6) & 63, h = (i >> 12) & 3, p = i >> 14;
        const float* W = (p == 0) ? Wq : (p == 1) ? Wk : Wv;
        float scale = (p == 0) ? QSCALE : 1.0f;
        float val = W[(h*64 + d)*64 + o] * scale;
        int idx = (((p*Hc + h)*64 + o) << 6) + d;
        __bf16 hi = (__bf16)val;
        Wbh[idx] = hi;
        Wbl[idx] = (__bf16)(val - (float)hi);
        if (i < 3*Hc*64) {
            int pp = i / (Hc*64), rest = i % (Hc*64);
            const float* B = (pp == 0) ? bq : (pp == 1) ? bk : bv;
            Bs[i] = B[rest] * ((pp == 0) ? QSCALE : 1.0f);
        }
    } else {
        int i = (blockIdx.x - 192)*256 + threadIdx.x;   // 49152 x 8 elems
        const float4* xp = (const float4*)(x + (size_t)i*8);
        float4 a = xp[0], c = xp[1];
        float v[8] = {a.x, a.y, a.z, a.w, c.x, c.y, c.z, c.w};
        bf16x8 h, l;
        #pragma unroll
        for (int j = 0; j < 8; ++j) {
            __bf16 hh = (__bf16)v[j];
            h[j] = hh;
            l[j] = (__bf16)(v[j] - (float)hh);
        }
        *(bf16x8*)(Xh + (size_t)i*8) = h;
        *(bf16x8*)(Xl + (size_t)i*8) = l;
    }
}

// ---- QKV projection via MFMA. Q -> hi only; K -> hi/lo flat; V -> image granules (hi) ----
__global__ __launch_bounds__(256) void qkv_mfma(
    const __bf16* __restrict__ Xh, const __bf16* __restrict__ Xl,
    const __bf16* __restrict__ Wbh, const __bf16* __restrict__ Wbl,
    const float* __restrict__ Bs,
    __bf16* __restrict__ Qh,
    __bf16* __restrict__ Kh, __bf16* __restrict__ Kl,
    __bf16* __restrict__ KVimg)
{
    const int lane = threadIdx.x & 63, w = threadIdx.x >> 6;
    const int l31 = lane & 31, hi = lane >> 5;
    int t = blockIdx.x;                 // 1152 blocks
    int nt = t % 48; t /= 48;
    int b  = t & 1;  t >>= 1;
    int p  = t % 3;
    int h  = t / 3;
    const int r0 = (w >> 1)*32, c0 = (w & 1)*32, n0 = nt*64;

    bf16x8 xh[4], xl[4], wh[4], wl[4];
    #pragma unroll
    for (int kk = 0; kk < 4; ++kk) {
        size_t xoff = (((size_t)(b*Nc + n0 + r0 + l31)) << 6) + kk*16 + hi*8;
        xh[kk] = *(const bf16x8*)(Xh + xoff);
        xl[kk] = *(const bf16x8*)(Xl + xoff);
        size_t woff = (((size_t)((p*Hc + h)*64 + c0 + l31)) << 6) + kk*16 + hi*8;
        wh[kk] = *(const bf16x8*)(Wbh + woff);
        wl[kk] = *(const bf16x8*)(Wbl + woff);
    }
    float bias = Bs[(p*Hc + h)*64 + c0 + l31];
    f32x16 acc;
    #pragma unroll
    for (int i = 0; i < 16; ++i) acc[i] = bias;
    #pragma unroll
    for (int kk = 0; kk < 4; ++kk) {
        acc = mfma32(xh[kk], wh[kk], acc);
        acc = mfma32(xl[kk], wh[kk], acc);
        acc = mfma32(xh[kk], wl[kk], acc);
    }
    const int bh = b*Hc + h;
    if (p == 0) {
        #pragma unroll
        for (int r = 0; r < 16; ++r) {
            int row = (r & 3) + 8*(r >> 2) + 4*hi;
            size_t idx = (((size_t)bh*Nc + n0 + r0 + row) << 6) + c0 + l31;
            Qh[idx] = (__bf16)acc[r];
        }
    } else if (p == 1) {
        #pragma unroll
        for (int r = 0; r < 16; ++r) {
            int row = (r & 3) + 8*(r >> 2) + 4*hi;
            size_t idx = (((size_t)bh*Nc + n0 + r0 + row) << 6) + c0 + l31;
            float val = acc[r];
            __bf16 hh = (__bf16)val;
            Kh[idx] = hh;
            Kl[idx] = (__bf16)(val - (float)hh);
        }
    } else {
        // V: write image granules directly (granule (kb,o) = V[kb*8..+7][o]), hi only
        const int t_img = (n0 + r0) >> 5;
        char* img = (char*)KVimg + (size_t)(bh*96 + t_img)*TILEB;
        #pragma unroll
        for (int grp = 0; grp < 2; ++grp) {       // acc regs grp*8 .. grp*8+7
            uint32_t wH[4];
            #pragma unroll
            for (int j = 0; j < 4; ++j)
                wH[j] = cvtpk(acc[grp*8 + 2*j], acc[grp*8 + 2*j + 1]);
            asm("v_permlane32_swap_b32 %0, %1" : "+v"(wH[0]), "+v"(wH[2]));
            asm("v_permlane32_swap_b32 %0, %1" : "+v"(wH[1]), "+v"(wH[3]));
            const int kb = grp*2 + hi;
            const int o  = c0 + l31;
            uint4 gh = {wH[0], wH[1], wH[2], wH[3]};
            *(uint4*)(img + 8192 + ((kb*64 + o) << 4)) = gh;
        }
    }
}

// ---- K image: granule (dc,key) = K[key][dc*8..+7] (hi at 0, lo at +4096) ----
__global__ void imgk_kernel(const __bf16* __restrict__ Kh, const __bf16* __restrict__ Kl,
                            __bf16* __restrict__ KVimg)
{
    const int tid = threadIdx.x;
    const int t = blockIdx.x % 96, bh = blockIdx.x / 96;
    char* img = (char*)KVimg + (size_t)(bh*96 + t)*TILEB;
    int dc = tid & 7, key = tid >> 3;
    size_t src = (((size_t)bh*Nc + t*32 + key) << 6) + dc*8;
    *(uint4*)(img + (dc*32 + key)*16)        = *(const uint4*)(Kh + src);
    *(uint4*)(img + 4096 + (dc*32 + key)*16) = *(const uint4*)(Kl + src);
}

// ---- pack adjacency transposed: pmT[b][w][n], bit j = edge[b][n][32w+j] ----
__global__ void pack_kernel(const int* __restrict__ edge, uint32_t* __restrict__ pmT)
{
    int gw = blockIdx.x*4 + (threadIdx.x >> 6);
    int lane = threadIdx.x & 63;
    int ng = gw % 48; gw /= 48;
    int w  = gw % NW32; gw /= NW32;
    int b  = gw;
    int n = ng*64 + lane;
    const uint4* ep = (const uint4*)(edge + ((size_t)b*Nc + n)*Nc + w*32);
    uint32_t word = 0;
    #pragma unroll
    for (int i = 0; i < 8; ++i) {
        uint4 e = ep[i];
        word |= (e.x ? 1u : 0u) << (4*i);
        word |= (e.y ? 1u : 0u) << (4*i + 1);
        word |= (e.z ? 1u : 0u) << (4*i + 2);
        word |= (e.w ? 1u : 0u) << (4*i + 3);
    }
    pmT[((size_t)b*NW32 + w)*Nc + n] = word;
}

// ---- flash attention: 32 q-rows/wave, 64-key iterations (2 sub-tiles/barrier),
//      14 MFMA per 32-key sub-tile (8 QK + 2 denom + 4 PV), counted-vmcnt pipeline ----
__global__ __launch_bounds__(256, 3) void attn_mfma(
    const __bf16* __restrict__ Qh,
    const __bf16* __restrict__ KVimg, const uint32_t* __restrict__ pmT,
    float* __restrict__ PA, float* __restrict__ PL, int KS, int tps)
{
    __shared__ __align__(16) char ldsKV[2][2*TILEB];   // 48 KB
    const int lane = threadIdx.x & 63, w = threadIdx.x >> 6;
    const int l31 = lane & 31, hi = lane >> 5;
    int gb = blockIdx.x;
    const int bh = gb & 7; gb >>= 3;        // XCD swizzle: one bh per XCD
    const int qt = gb % 24;
    const int ks = gb / 24;
    const int b = bh >> 2;
    const int qrow0 = qt*128 + w*32;
    const int t0 = ks*tps;                  // in 32-key tiles
    const int iters = tps >> 1;             // 64-key iterations

    // masks for tiles t0, t0+1, loaded BEFORE stage (in-order vmcnt retirement)
    const uint32_t* pmp = pmT + ((size_t)b*NW32 + t0)*Nc + qrow0 + l31;
    uint32_t mwA = pmp[0];
    uint32_t mwB = pmp[Nc];
    __builtin_amdgcn_sched_barrier(0);
    const char* gsrc = (const char*)KVimg + (size_t)(bh*96 + t0)*TILEB
                     + w*6144 + lane*16;
    #pragma unroll
    for (int g = 0; g < 6; ++g)
        gload_lds16(gsrc + g*1024, &ldsKV[0][w*6144 + g*1024]);

    // Q B-frags (col = q-row = l31, k = d), pre-scaled by QSCALE, hi only
    bf16x8 qh[4];
    #pragma unroll
    for (int kk = 0; kk < 4; ++kk) {
        size_t qoff = (((size_t)bh*Nc + qrow0 + l31) << 6) + kk*16 + hi*8;
        qh[kk] = *(const bf16x8*)(Qh + qoff);
    }
    bf16x8 ones;
    #pragma unroll
    for (int j = 0; j < 8; ++j) ones[j] = (__bf16)1.0f;

    f32x16 acc0, acc1, acc2;
    #pragma unroll
    for (int i = 0; i < 16; ++i) { acc0[i] = 0.f; acc1[i] = 0.f; acc2[i] = 0.f; }

    int cur = 0;
    #pragma unroll 1
    for (int it = 0; it < iters; ++it) {
        const size_t moff = (size_t)((it + 1 < iters) ? 2 : 0) * Nc;
        // prefetch next masks FIRST, then next stage: vmcnt(8) retires current tile
        uint32_t nmwA = pmp[moff];
        uint32_t nmwB = pmp[moff + Nc];
        pmp += moff;
        __builtin_amdgcn_sched_barrier(0);
        const char* gnext = gsrc + ((it + 1 < iters) ? 2*TILEB : 0);
        {
            char* ldst = &ldsKV[cur ^ 1][w*6144];
            #pragma unroll
            for (int g = 0; g < 6; ++g)
                gload_lds16(gnext + g*1024, ldst + g*1024);
        }
        gsrc = gnext;
        asm volatile("s_waitcnt vmcnt(8)" ::: "memory");
        __builtin_amdgcn_s_barrier();

        #pragma unroll
        for (int u = 0; u < 2; ++u) {
            const char* Lb = &ldsKV[cur][u*TILEB];
            const uint32_t mw = u ? mwB : mwA;

            // ---- QK^T: 8 MFMA  (S = qh·(kh + kl), split-K precision) ----
            f32x16 sc;
            #pragma unroll
            for (int i = 0; i < 16; ++i) sc[i] = 0.f;
            __builtin_amdgcn_s_setprio(1);
            #pragma unroll
            for (int kk = 0; kk < 4; ++kk) {
                bf16x8 ka = *(const bf16x8*)(Lb + ((kk*2 + hi) << 9) + (l31 << 4));
                bf16x8 la = *(const bf16x8*)(Lb + 4096 + ((kk*2 + hi) << 9) + (l31 << 4));
                sc = mfma32(ka, qh[kk], sc);
                sc = mfma32(la, qh[kk], sc);
            }
            __builtin_amdgcn_s_setprio(0);

            // ---- in-register softmax -> masked packed bf16 pairs ----
            uint32_t W8[8];
            softmax_pack(sc, mw >> (hi*4), W8);
            bf16x8 pa0, pa1;
            assemble_pa(W8, pa0, pa1);

            // ---- denominator (2 MFMA, ones) + PV (4 MFMA, V hi only) ----
            __builtin_amdgcn_s_setprio(1);
            acc2 = mfma32(pa0, ones, acc2);
            acc2 = mfma32(pa1, ones, acc2);
            #pragma unroll
            for (int kkp = 0; kkp < 2; ++kkp) {
                bf16x8 pa = kkp ? pa1 : pa0;
                #pragma unroll
                for (int ot = 0; ot < 2; ++ot) {
                    bf16x8 vh = *(const bf16x8*)(Lb + 8192 + ((kkp*2 + hi) << 10)
                                                 + ((ot*32 + l31) << 4));
                    if (ot == 0) acc0 = mfma32(pa, vh, acc0);
                    else         acc1 = mfma32(pa, vh, acc1);
                }
            }
            __builtin_amdgcn_s_setprio(0);
        }
        mwA = nmwA; mwB = nmwB;

        asm volatile("" ::: "memory");
        __builtin_amdgcn_s_barrier();
        cur ^= 1;
    }

    // ---- epilogue: PA[bh][ks][n][o], PL[bh][ks][n] (rowsums in acc2) ----
    float* po = PA + (((size_t)(bh*KS + ks)*Nc + qrow0) << 6);
    #pragma unroll
    for (int r = 0; r < 16; ++r) {
        int row = (r & 3) + 8*(r >> 2) + 4*hi;
        po[((size_t)row << 6) + l31]      = acc0[r];
        po[((size_t)row << 6) + 32 + l31] = acc1[r];
    }
    if (l31 == 0) {
        float* pl = PL + (size_t)(bh*KS + ks)*Nc + qrow0;
        #pragma unroll
        for (int r = 0; r < 16; ++r)
            pl[(r & 3) + 8*(r >> 2) + 4*hi] = acc2[r];
    }
}

// ---- merge: sum key-splits, divide, mean heads, leaky ----
__global__ void merge_kernel(const float* __restrict__ PA, const float* __restrict__ PL,
                             float* __restrict__ out, int KS)
{
    int gid = blockIdx.x*256 + threadIdx.x;
    int o  = gid & 63;
    int bn = gid >> 6;
    int n  = bn % Nc;
    int b  = bn / Nc;
    float ft = 0.f;
    for (int h = 0; h < Hc; ++h) {
        int bh = b*Hc + h;
        float A = 0.f, L = 0.f;
        for (int ks = 0; ks < KS; ++ks) {
            A += PA[(((size_t)(bh*KS + ks)*Nc + n) << 6) + o];
            L += PL[(size_t)(bh*KS + ks)*Nc + n];
        }
        ft += A / L;
    }
    ft *= 0.25f;
    out[((size_t)bn << 6) + o] = fmaxf(ft, 0.f) + 0.2f*fminf(ft, 0.f);
}

extern "C" void kernel_launch(void* const* d_in, const int* in_sizes, int n_in,
                              void* d_out, int out_size, void* d_ws, size_t ws_size,
                              hipStream_t stream)
{
    const float* x    = (const float*)d_in[0];
    const int*   edge = (const int*)d_in[1];
    const float* Wv   = (const float*)d_in[2];
    const float* bv   = (const float*)d_in[3];
    const float* Wq   = (const float*)d_in[4];
    const float* bq   = (const float*)d_in[5];
    const float* Wk   = (const float*)d_in[6];
    const float* bk   = (const float*)d_in[7];
    float* out = (float*)d_out;

    const size_t PROJ = (size_t)Bc*Hc*Nc*64;
    char* p = (char*)d_ws;
    __bf16* Wbh = (__bf16*)p;   p += 49152*2;
    __bf16* Wbl = (__bf16*)p;   p += 49152*2;
    float*  Bs  = (float*)p;    p += 4096;
    __bf16* Xh  = (__bf16*)p;   p += (size_t)Bc*Nc*64*2;
    __bf16* Xl  = (__bf16*)p;   p += (size_t)Bc*Nc*64*2;
    __bf16* Qh  = (__bf16*)p;   p += PROJ*2;
    __bf16* Kh  = (__bf16*)p;   p += PROJ*2;
    __bf16* Kl  = (__bf16*)p;   p += PROJ*2;
    __bf16* KVimg = (__bf16*)p; p += (size_t)Bc*Hc*96*TILEB;
    uint32_t* pmT = (uint32_t*)p; p += (size_t)Bc*NW32*Nc*4;

    int KS = 4;   // grid 768 = 3 blocks/CU
    for (;;) {
        size_t need = (size_t)(p - (char*)d_ws)
                    + (size_t)Bc*Hc*KS*Nc*64*4 + (size_t)Bc*Hc*KS*Nc*4;
        if (need <= ws_size || KS == 1) break;
        KS >>= 1;
    }
    float* PA = (float*)p;      p += (size_t)Bc*Hc*KS*Nc*64*4;
    float* PL = (float*)p;

    hipLaunchKernelGGL(prep_kernel, dim3(384),  dim3(256), 0, stream,
                       Wq, Wk, Wv, bq, bk, bv, x, Wbh, Wbl, Bs, Xh, Xl);
    hipLaunchKernelGGL(qkv_mfma,    dim3(1152), dim3(256), 0, stream,
                       Xh, Xl, Wbh, Wbl, Bs, Qh, Kh, Kl, KVimg);
    hipLaunchKernelGGL(imgk_kernel, dim3(Bc*Hc*96), dim3(256), 0, stream, Kh, Kl, KVimg);
    hipLaunchKernelGGL(pack_kernel, dim3(Bc*NW32*48/4), dim3(256), 0, stream, edge, pmT);
    hipLaunchKernelGGL(attn_mfma,   dim3(8*KS*24), dim3(256), 0, stream,
                       Qh, KVimg, pmT, PA, PL, KS, 96/KS);
    hipLaunchKernelGGL(merge_kernel, dim3((Bc*Nc*64)/256), dim3(256), 0, stream,
                       PA, PL, out, KS);
}

// Round 9
// 80.934 us; speedup vs baseline: 1.3616x; 1.1019x over previous
//
#include <hip/hip_runtime.h>
#include <hip/hip_bf16.h>
#include <cstdint>

#define Bc 2
#define Nc 3072
#define Hc 4
#define NW32 96      // 32-key tiles per row
#define TILEB 8192   // per 32-key fp16 image tile: K 4KB | V 4KB

typedef __bf16    bf16x8 __attribute__((ext_vector_type(8)));
typedef _Float16  f16x8  __attribute__((ext_vector_type(8)));
typedef float     f32x16 __attribute__((ext_vector_type(16)));

#define QSCALE 0.18033688f   // 0.125 * log2(e): exp(s/8) == exp2(s*QSCALE)

static __device__ __forceinline__ f32x16 mfma32bf(bf16x8 a, bf16x8 b, f32x16 c) {
    return __builtin_amdgcn_mfma_f32_32x32x16_bf16(a, b, c, 0, 0, 0);
}
static __device__ __forceinline__ f32x16 mfma32h(f16x8 a, f16x8 b, f32x16 c) {
    return __builtin_amdgcn_mfma_f32_32x32x16_f16(a, b, c, 0, 0, 0);
}
static __device__ __forceinline__ void gload_lds16(const void* g, void* l) {
    __builtin_amdgcn_global_load_lds((const __attribute__((address_space(1))) void*)g,
                                     (__attribute__((address_space(3))) void*)l, 16, 0, 0);
}
static __device__ __forceinline__ uint32_t pkrtz(float lo, float hi) {
    uint32_t w;
    asm("v_cvt_pkrtz_f16_f32 %0, %1, %2" : "=v"(w) : "v"(lo), "v"(hi));
    return w;
}

// softmax for one 32-key sub-tile: leaky+exp2, mask floats, pack to f16 pairs,
// denominator sums the masked floats (numerator uses RTZ-packed: rel mismatch <= 2^-10).
static __device__ __forceinline__ void softmax_pack(const f32x16& sc, uint32_t mwh,
                                                    uint32_t W8[8], float& lsum)
{
    #pragma unroll
    for (int i = 0; i < 8; ++i) {
        const int bp0 = (2*i & 3) + 8*(2*i >> 2);   // bp1 = bp0+1
        float s0 = sc[2*i], s1 = sc[2*i + 1];
        float a0 = fmaxf(s0, 0.2f*s0);
        float a1 = fmaxf(s1, 0.2f*s1);
        float e0, e1;
        asm("v_exp_f32 %0, %1" : "=v"(e0) : "v"(a0));   // exp2 (log2e pre-folded)
        asm("v_exp_f32 %0, %1" : "=v"(e1) : "v"(a1));
        uint32_t m0 = (uint32_t)(((int)(mwh << (31 - bp0))) >> 31);
        uint32_t m1 = (uint32_t)(((int)(mwh << (30 - bp0))) >> 31);
        float p0 = __uint_as_float(__float_as_uint(e0) & m0);
        float p1 = __uint_as_float(__float_as_uint(e1) & m1);
        lsum += p0 + p1;
        W8[i] = pkrtz(p0, p1);
    }
}

static __device__ __forceinline__ void assemble_pa(uint32_t W8[8], f16x8& pa0, f16x8& pa1)
{
    uint32_t a0 = W8[0], a2 = W8[2], a1 = W8[1], a3 = W8[3];
    uint32_t b0 = W8[4], b2 = W8[6], b1 = W8[5], b3 = W8[7];
    asm("v_permlane32_swap_b32 %0, %1" : "+v"(a0), "+v"(a2));
    asm("v_permlane32_swap_b32 %0, %1" : "+v"(a1), "+v"(a3));
    asm("v_permlane32_swap_b32 %0, %1" : "+v"(b0), "+v"(b2));
    asm("v_permlane32_swap_b32 %0, %1" : "+v"(b1), "+v"(b3));
    union { uint32_t u[4]; f16x8 v; } u0, u1;
    u0.u[0] = a0; u0.u[1] = a1; u0.u[2] = a2; u0.u[3] = a3;
    u1.u[0] = b0; u1.u[1] = b1; u1.u[2] = b2; u1.u[3] = b3;
    pa0 = u0.v; pa1 = u1.v;
}

// ---- fused prep: W -> bf16 hi/lo [p][h][o][d] (+bias), x -> bf16 hi/lo planes ----
__global__ void prep_kernel(const float* __restrict__ Wq, const float* __restrict__ Wk,
                            const float* __restrict__ Wv,
                            const float* __restrict__ bq, const float* __restrict__ bk,
                            const float* __restrict__ bv, const float* __restrict__ x,
                            __bf16* __restrict__ Wbh, __bf16* __restrict__ Wbl,
                            float* __restrict__ Bs,
                            __bf16* __restrict__ Xh, __bf16* __restrict__ Xl)
{
    if (blockIdx.x < 192) {
        int i = blockIdx.x*256 + threadIdx.x;   // 49152
        int d = i & 63, o = (i >> 6) & 63, h = (i >> 12) & 3, p = i >> 14;
        const float* W = (p == 0) ? Wq : (p == 1) ? Wk : Wv;
        float scale = (p == 0) ? QSCALE : 1.0f;
        float val = W[(h*64 + d)*64 + o] * scale;
        int idx = (((p*Hc + h)*64 + o) << 6) + d;
        __bf16 hi = (__bf16)val;
        Wbh[idx] = hi;
        Wbl[idx] = (__bf16)(val - (float)hi);
        if (i < 3*Hc*64) {
            int pp = i / (Hc*64), rest = i % (Hc*64);
            const float* B = (pp == 0) ? bq : (pp == 1) ? bk : bv;
            Bs[i] = B[rest] * ((pp == 0) ? QSCALE : 1.0f);
        }
    } else {
        int i = (blockIdx.x - 192)*256 + threadIdx.x;   // 49152 x 8 elems
        const float4* xp = (const float4*)(x + (size_t)i*8);
        float4 a = xp[0], c = xp[1];
        float v[8] = {a.x, a.y, a.z, a.w, c.x, c.y, c.z, c.w};
        bf16x8 h, l;
        #pragma unroll
        for (int j = 0; j < 8; ++j) {
            __bf16 hh = (__bf16)v[j];
            h[j] = hh;
            l[j] = (__bf16)(v[j] - (float)hh);
        }
        *(bf16x8*)(Xh + (size_t)i*8) = h;
        *(bf16x8*)(Xl + (size_t)i*8) = l;
    }
}

// ---- QKV projection via MFMA (split-bf16 accuracy). Q,K -> fp16 flat; V -> image fp16 ----
__global__ __launch_bounds__(256) void qkv_mfma(
    const __bf16* __restrict__ Xh, const __bf16* __restrict__ Xl,
    const __bf16* __restrict__ Wbh, const __bf16* __restrict__ Wbl,
    const float* __restrict__ Bs,
    _Float16* __restrict__ Qf, _Float16* __restrict__ Kf,
    _Float16* __restrict__ KVimg)
{
    const int lane = threadIdx.x & 63, w = threadIdx.x >> 6;
    const int l31 = lane & 31, hi = lane >> 5;
    int t = blockIdx.x;                 // 1152 blocks
    int nt = t % 48; t /= 48;
    int b  = t & 1;  t >>= 1;
    int p  = t % 3;
    int h  = t / 3;
    const int r0 = (w >> 1)*32, c0 = (w & 1)*32, n0 = nt*64;

    bf16x8 xh[4], xl[4], wh[4], wl[4];
    #pragma unroll
    for (int kk = 0; kk < 4; ++kk) {
        size_t xoff = (((size_t)(b*Nc + n0 + r0 + l31)) << 6) + kk*16 + hi*8;
        xh[kk] = *(const bf16x8*)(Xh + xoff);
        xl[kk] = *(const bf16x8*)(Xl + xoff);
        size_t woff = (((size_t)((p*Hc + h)*64 + c0 + l31)) << 6) + kk*16 + hi*8;
        wh[kk] = *(const bf16x8*)(Wbh + woff);
        wl[kk] = *(const bf16x8*)(Wbl + woff);
    }
    float bias = Bs[(p*Hc + h)*64 + c0 + l31];
    f32x16 acc;
    #pragma unroll
    for (int i = 0; i < 16; ++i) acc[i] = bias;
    #pragma unroll
    for (int kk = 0; kk < 4; ++kk) {
        acc = mfma32bf(xh[kk], wh[kk], acc);
        acc = mfma32bf(xl[kk], wh[kk], acc);
        acc = mfma32bf(xh[kk], wl[kk], acc);
    }
    const int bh = b*Hc + h;
    if (p < 2) {
        _Float16* dst = (p == 0) ? Qf : Kf;
        #pragma unroll
        for (int r = 0; r < 16; ++r) {
            int row = (r & 3) + 8*(r >> 2) + 4*hi;
            size_t idx = (((size_t)bh*Nc + n0 + r0 + row) << 6) + c0 + l31;
            dst[idx] = (_Float16)acc[r];
        }
    } else {
        // V: write image granules directly (granule (kb,o) = V[kb*8..+7][o]) in fp16
        const int t_img = (n0 + r0) >> 5;
        char* img = (char*)KVimg + (size_t)(bh*96 + t_img)*TILEB;
        #pragma unroll
        for (int grp = 0; grp < 2; ++grp) {       // acc regs grp*8 .. grp*8+7
            uint32_t wH[4];
            #pragma unroll
            for (int j = 0; j < 4; ++j)
                wH[j] = pkrtz(acc[grp*8 + 2*j], acc[grp*8 + 2*j + 1]);
            asm("v_permlane32_swap_b32 %0, %1" : "+v"(wH[0]), "+v"(wH[2]));
            asm("v_permlane32_swap_b32 %0, %1" : "+v"(wH[1]), "+v"(wH[3]));
            const int kb = grp*2 + hi;
            const int o  = c0 + l31;
            uint4 gh = {wH[0], wH[1], wH[2], wH[3]};
            *(uint4*)(img + 4096 + ((kb*64 + o) << 4)) = gh;
        }
    }
}

// ---- K image: granule (dc,key) = K[key][dc*8..+7] fp16, at tile offset 0 ----
__global__ void imgk_kernel(const _Float16* __restrict__ Kf, _Float16* __restrict__ KVimg)
{
    const int t = blockIdx.x % 96, bh = blockIdx.x / 96;
    char* img = (char*)KVimg + (size_t)(bh*96 + t)*TILEB;
    int dc = threadIdx.x & 7, key = threadIdx.x >> 3;
    size_t src = (((size_t)bh*Nc + t*32 + key) << 6) + dc*8;
    *(uint4*)(img + (dc*32 + key)*16) = *(const uint4*)(Kf + src);
}

// ---- pack adjacency transposed: pmT[b][w][n], bit j = edge[b][n][32w+j] ----
__global__ void pack_kernel(const int* __restrict__ edge, uint32_t* __restrict__ pmT)
{
    int gw = blockIdx.x*4 + (threadIdx.x >> 6);
    int lane = threadIdx.x & 63;
    int ng = gw % 48; gw /= 48;
    int w  = gw % NW32; gw /= NW32;
    int b  = gw;
    int n = ng*64 + lane;
    const uint4* ep = (const uint4*)(edge + ((size_t)b*Nc + n)*Nc + w*32);
    uint32_t word = 0;
    #pragma unroll
    for (int i = 0; i < 8; ++i) {
        uint4 e = ep[i];
        word |= (e.x ? 1u : 0u) << (4*i);
        word |= (e.y ? 1u : 0u) << (4*i + 1);
        word |= (e.z ? 1u : 0u) << (4*i + 2);
        word |= (e.w ? 1u : 0u) << (4*i + 3);
    }
    pmT[((size_t)b*NW32 + w)*Nc + n] = word;
}

// ---- flash attention fp16: 64-key iters, 3-buffer single-barrier pipeline,
//      8 MFMA per 32-key sub-tile (4 QK + 4 PV), denom via VALU ----
__global__ __launch_bounds__(256, 3) void attn_mfma(
    const _Float16* __restrict__ Qf,
    const _Float16* __restrict__ KVimg, const uint32_t* __restrict__ pmT,
    float* __restrict__ PA, float* __restrict__ PL, int KS, int tps)
{
    __shared__ __align__(16) char lds[3][2*TILEB];   // 48 KB, 3 x 16KB key-pair buffers
    const int lane = threadIdx.x & 63, w = threadIdx.x >> 6;
    const int l31 = lane & 31, hi = lane >> 5;
    int gb = blockIdx.x;
    const int bh = gb & 7; gb >>= 3;        // XCD swizzle: one bh per XCD
    const int qt = gb % 24;
    const int ks = gb / 24;
    const int b = bh >> 2;
    const int qrow0 = qt*128 + w*32;
    const int t0 = ks*tps;                  // in 32-key tiles
    const int iters = tps >> 1;             // 64-key iterations

    // masks for tiles t0,t0+1, loaded BEFORE stage (in-order vmcnt retirement)
    const uint32_t* pmp = pmT + ((size_t)b*NW32 + t0)*Nc + qrow0 + l31;
    uint32_t mw0 = pmp[0];
    uint32_t mw1 = pmp[Nc];
    __builtin_amdgcn_sched_barrier(0);
    const char* gsrc = (const char*)KVimg + (size_t)(bh*96 + t0)*TILEB
                     + w*4096 + lane*16;
    #pragma unroll
    for (int g = 0; g < 4; ++g)
        gload_lds16(gsrc + g*1024, &lds[0][w*4096 + g*1024]);

    // Q B-frags (col = q-row = l31, k = d), pre-scaled by QSCALE, fp16
    f16x8 qf[4];
    #pragma unroll
    for (int kk = 0; kk < 4; ++kk) {
        size_t qoff = (((size_t)bh*Nc + qrow0 + l31) << 6) + kk*16 + hi*8;
        qf[kk] = *(const f16x8*)(Qf + qoff);
    }

    f32x16 acc0, acc1;
    #pragma unroll
    for (int i = 0; i < 16; ++i) { acc0[i] = 0.f; acc1[i] = 0.f; }
    float lsum = 0.f;

    char *bA = &lds[0][0], *bB = &lds[1][0], *bC = &lds[2][0];
    #pragma unroll 1
    for (int it = 0; it < iters; ++it) {
        const int adv = (it + 1 < iters) ? 1 : 0;
        const size_t moff = (size_t)(adv ? 2 : 0) * Nc;
        uint32_t nmw0 = pmp[moff];
        uint32_t nmw1 = pmp[moff + Nc];
        pmp += moff;
        __builtin_amdgcn_sched_barrier(0);
        const char* gnext = gsrc + (adv ? 2*TILEB : 0);
        {
            char* ldst = bB + w*4096;
            #pragma unroll
            for (int g = 0; g < 4; ++g)
                gload_lds16(gnext + g*1024, ldst + g*1024);
        }
        gsrc = gnext;
        asm volatile("s_waitcnt vmcnt(6)" ::: "memory");
        __builtin_amdgcn_s_barrier();

        // ---- QK^T both sub-tiles: 8 MFMA, 2 independent chains ----
        f32x16 sc0, sc1;
        #pragma unroll
        for (int i = 0; i < 16; ++i) { sc0[i] = 0.f; sc1[i] = 0.f; }
        __builtin_amdgcn_s_setprio(1);
        #pragma unroll
        for (int kk = 0; kk < 4; ++kk) {
            f16x8 k0 = *(const f16x8*)(bA + ((kk*2 + hi) << 9) + (l31 << 4));
            f16x8 k1 = *(const f16x8*)(bA + TILEB + ((kk*2 + hi) << 9) + (l31 << 4));
            sc0 = mfma32h(k0, qf[kk], sc0);
            sc1 = mfma32h(k1, qf[kk], sc1);
        }
        __builtin_amdgcn_s_setprio(0);

        // ---- softmax both sub-tiles ----
        uint32_t W80[8], W81[8];
        softmax_pack(sc0, mw0 >> (hi*4), W80, lsum);
        softmax_pack(sc1, mw1 >> (hi*4), W81, lsum);
        mw0 = nmw0; mw1 = nmw1;
        f16x8 pa00, pa01, pa10, pa11;
        assemble_pa(W80, pa00, pa01);
        assemble_pa(W81, pa10, pa11);

        // ---- PV: 8 MFMA ----
        __builtin_amdgcn_s_setprio(1);
        #pragma unroll
        for (int u = 0; u < 2; ++u) {
            #pragma unroll
            for (int kkp = 0; kkp < 2; ++kkp) {
                f16x8 pa = u ? (kkp ? pa11 : pa10) : (kkp ? pa01 : pa00);
                #pragma unroll
                for (int ot = 0; ot < 2; ++ot) {
                    f16x8 vh = *(const f16x8*)(bA + u*TILEB + 4096
                                               + ((kkp*2 + hi) << 10)
                                               + ((ot*32 + l31) << 4));
                    if (ot == 0) acc0 = mfma32h(pa, vh, acc0);
                    else         acc1 = mfma32h(pa, vh, acc1);
                }
            }
        }
        __builtin_amdgcn_s_setprio(0);

        // rotate 3 buffers; no second barrier needed (stage target is never
        // concurrently read: all waves passed this iter's barrier => they
        // finished the compute that last touched the new stage target)
        char* tmp = bA; bA = bB; bB = bC; bC = tmp;
    }

    // ---- epilogue: PA[bh][ks][n][o], PL[bh][ks][n] ----
    float* po = PA + (((size_t)(bh*KS + ks)*Nc + qrow0) << 6);
    #pragma unroll
    for (int r = 0; r < 16; ++r) {
        int row = (r & 3) + 8*(r >> 2) + 4*hi;
        po[((size_t)row << 6) + l31]      = acc0[r];
        po[((size_t)row << 6) + 32 + l31] = acc1[r];
    }
    lsum += __shfl_xor(lsum, 32);
    if (lane < 32)
        PL[(size_t)(bh*KS + ks)*Nc + qrow0 + l31] = lsum;
}

// ---- merge: sum key-splits, divide, mean heads, leaky ----
__global__ void merge_kernel(const float* __restrict__ PA, const float* __restrict__ PL,
                             float* __restrict__ out, int KS)
{
    int gid = blockIdx.x*256 + threadIdx.x;
    int o  = gid & 63;
    int bn = gid >> 6;
    int n  = bn % Nc;
    int b  = bn / Nc;
    float ft = 0.f;
    for (int h = 0; h < Hc; ++h) {
        int bh = b*Hc + h;
        float A = 0.f, L = 0.f;
        for (int ks = 0; ks < KS; ++ks) {
            A += PA[(((size_t)(bh*KS + ks)*Nc + n) << 6) + o];
            L += PL[(size_t)(bh*KS + ks)*Nc + n];
        }
        ft += A / L;
    }
    ft *= 0.25f;
    out[((size_t)bn << 6) + o] = fmaxf(ft, 0.f) + 0.2f*fminf(ft, 0.f);
}

extern "C" void kernel_launch(void* const* d_in, const int* in_sizes, int n_in,
                              void* d_out, int out_size, void* d_ws, size_t ws_size,
                              hipStream_t stream)
{
    const float* x    = (const float*)d_in[0];
    const int*   edge = (const int*)d_in[1];
    const float* Wv   = (const float*)d_in[2];
    const float* bv   = (const float*)d_in[3];
    const float* Wq   = (const float*)d_in[4];
    const float* bq   = (const float*)d_in[5];
    const float* Wk   = (const float*)d_in[6];
    const float* bk   = (const float*)d_in[7];
    float* out = (float*)d_out;

    const size_t PROJ = (size_t)Bc*Hc*Nc*64;
    char* p = (char*)d_ws;
    __bf16* Wbh = (__bf16*)p;     p += 49152*2;
    __bf16* Wbl = (__bf16*)p;     p += 49152*2;
    float*  Bs  = (float*)p;      p += 4096;
    __bf16* Xh  = (__bf16*)p;     p += (size_t)Bc*Nc*64*2;
    __bf16* Xl  = (__bf16*)p;     p += (size_t)Bc*Nc*64*2;
    _Float16* Qf = (_Float16*)p;  p += PROJ*2;
    _Float16* Kf = (_Float16*)p;  p += PROJ*2;
    _Float16* KVimg = (_Float16*)p; p += (size_t)Bc*Hc*96*TILEB;
    uint32_t* pmT = (uint32_t*)p; p += (size_t)Bc*NW32*Nc*4;

    int KS = 4;   // grid 768 = 3 blocks/CU exactly
    for (;;) {
        size_t need = (size_t)(p - (char*)d_ws)
                    + (size_t)Bc*Hc*KS*Nc*64*4 + (size_t)Bc*Hc*KS*Nc*4;
        if (need <= ws_size || KS == 1) break;
        KS >>= 1;
    }
    float* PA = (float*)p;        p += (size_t)Bc*Hc*KS*Nc*64*4;
    float* PL = (float*)p;

    hipLaunchKernelGGL(prep_kernel, dim3(384),  dim3(256), 0, stream,
                       Wq, Wk, Wv, bq, bk, bv, x, Wbh, Wbl, Bs, Xh, Xl);
    hipLaunchKernelGGL(qkv_mfma,    dim3(1152), dim3(256), 0, stream,
                       Xh, Xl, Wbh, Wbl, Bs, Qf, Kf, KVimg);
    hipLaunchKernelGGL(imgk_kernel, dim3(Bc*Hc*96), dim3(256), 0, stream, Kf, KVimg);
    hipLaunchKernelGGL(pack_kernel, dim3(Bc*NW32*48/4), dim3(256), 0, stream, edge, pmT);
    hipLaunchKernelGGL(attn_mfma,   dim3(8*KS*24), dim3(256), 0, stream,
                       Qf, KVimg, pmT, PA, PL, KS, 96/KS);
    hipLaunchKernelGGL(merge_kernel, dim3((Bc*Nc*64)/256), dim3(256), 0, stream,
                       PA, PL, out, KS);
}